// Round 8
// baseline (36.428 us; speedup 1.0000x reference)
//
#include <hip/hip_runtime.h>
#include <math.h>

// Problem constants (from reference: x = (2,2,160,160,160) fp32)
#define BCn 4
#define Dn 160
#define Hn 160
#define Wn 160
#define HWn (Hn * Wn)
#define W4q (Wn / 4)        // 40 float4 groups per row
#define H2 (Hn / 2)         // 80 row-pairs
#define COLS2 (H2 * W4q)    // 3200 (row-pair, q) columns per plane
#define DCHUNK 5
#define BLOCK 128

// Native clang vector type: __builtin_nontemporal_store requires it
// (HIP's float4 is a class and is rejected — R7 compile failure).
typedef float f32x4 __attribute__((ext_vector_type(4)));

// Reduced per-plane state for 4 consecutive W outputs of one output row:
//   Rs = 3x3 window sums (feeds gd), Rd = row(h+1)-row(h-1) sums (feeds gh),
//   Cs = col(w+1)-col(w-1) sums (feeds gw).
struct Plane {
  float4 Rs, Rd, Cs;
};
struct Plane2 {
  Plane a, b;  // output rows h0 and h0+1
};

__device__ __forceinline__ Plane mk_plane(float s0, float s1, float s2,
                                          float s3, float s4, float s5,
                                          float d0, float d1, float d2,
                                          float d3, float d4, float d5) {
  Plane o;
  const float t12 = s1 + s2, t23 = s2 + s3, t34 = s3 + s4;
  o.Rs.x = s0 + t12;
  o.Rs.y = t12 + s3;
  o.Rs.z = t23 + s4;
  o.Rs.w = t34 + s5;
  const float u12 = d1 + d2, u23 = d2 + d3, u34 = d3 + d4;
  o.Rd.x = d0 + u12;
  o.Rd.y = u12 + d3;
  o.Rd.z = u23 + d4;
  o.Rd.w = u34 + d5;
  o.Cs.x = s2 - s0;
  o.Cs.y = s3 - s1;
  o.Cs.z = s4 - s2;
  o.Cs.w = s5 - s3;
  return o;
}

// One z-plane for a 2-row x 4-col output group: 4 coalesced float4 loads
// (input rows h0-1 .. h0+2), halo from neighbor lanes via shuffle.
__device__ __forceinline__ Plane2 load_plane2(
    const float* __restrict__ xb, int zz, int rA, int rB, int rC, int rD,
    int w4, bool ql, bool qr, bool fixL, bool fixR) {
  const int zc = zz < 0 ? 0 : (zz > Dn - 1 ? Dn - 1 : zz);
  const float* p = xb + (size_t)zc * HWn;

  const float4 A = *(const float4*)(p + rA + w4);
  const float4 B = *(const float4*)(p + rB + w4);
  const float4 C = *(const float4*)(p + rC + w4);
  const float4 D = *(const float4*)(p + rD + w4);

  // Cross-lane halo (uniform control flow: whole wave executes).
  float lA = __shfl_up(A.w, 1), rAe = __shfl_down(A.x, 1);
  float lB = __shfl_up(B.w, 1), rBe = __shfl_down(B.x, 1);
  float lC = __shfl_up(C.w, 1), rCe = __shfl_down(C.x, 1);
  float lD = __shfl_up(D.w, 1), rDe = __shfl_down(D.x, 1);

  // Wave-boundary fixups (1 active lane -> ~1 line-touch each).
  if (fixL) {
    lA = p[rA + w4 - 1];
    lB = p[rB + w4 - 1];
    lC = p[rC + w4 - 1];
    lD = p[rD + w4 - 1];
  }
  if (fixR) {
    rAe = p[rA + w4 + 4];
    rBe = p[rB + w4 + 4];
    rCe = p[rC + w4 + 4];
    rDe = p[rD + w4 + 4];
  }

  // Replicate clamp at row edges.
  const float A0 = ql ? A.x : lA, A5 = qr ? A.w : rAe;
  const float B0 = ql ? B.x : lB, B5 = qr ? B.w : rBe;
  const float C0 = ql ? C.x : lC, C5 = qr ? C.w : rCe;
  const float D0 = ql ? D.x : lD, D5 = qr ? D.w : rDe;

  // Shared middle-row sums (rows B+C serve both output rows).
  const float bc0 = B0 + C0;
  const float bc1 = B.x + C.x;
  const float bc2 = B.y + C.y;
  const float bc3 = B.z + C.z;
  const float bc4 = B.w + C.w;
  const float bc5 = B5 + C5;

  Plane2 out;
  // Output row h0: rows A,B,C. s = bc + A, d = C - A.
  out.a = mk_plane(bc0 + A0, bc1 + A.x, bc2 + A.y, bc3 + A.z, bc4 + A.w,
                   bc5 + A5,
                   C0 - A0, C.x - A.x, C.y - A.y, C.z - A.z, C.w - A.w,
                   C5 - A5);
  // Output row h0+1: rows B,C,D. s = bc + D, d = D - B.
  out.b = mk_plane(bc0 + D0, bc1 + D.x, bc2 + D.y, bc3 + D.z, bc4 + D.w,
                   bc5 + D5,
                   D0 - B0, D.x - B.x, D.y - B.y, D.z - B.z, D.w - B.w,
                   D5 - B5);
  return out;
}

__device__ __forceinline__ f32x4 mag4(const Plane& P0, const Plane& P1,
                                      const Plane& P2) {
  const float gdx = P2.Rs.x - P0.Rs.x;
  const float gdy = P2.Rs.y - P0.Rs.y;
  const float gdz = P2.Rs.z - P0.Rs.z;
  const float gdw = P2.Rs.w - P0.Rs.w;
  const float ghx = P0.Rd.x + P1.Rd.x + P2.Rd.x;
  const float ghy = P0.Rd.y + P1.Rd.y + P2.Rd.y;
  const float ghz = P0.Rd.z + P1.Rd.z + P2.Rd.z;
  const float ghw = P0.Rd.w + P1.Rd.w + P2.Rd.w;
  const float gwx = P0.Cs.x + P1.Cs.x + P2.Cs.x;
  const float gwy = P0.Cs.y + P1.Cs.y + P2.Cs.y;
  const float gwz = P0.Cs.z + P1.Cs.z + P2.Cs.z;
  const float gww = P0.Cs.w + P1.Cs.w + P2.Cs.w;
  f32x4 g;
  // Raw v_sqrt_f32 — abs threshold is 0.555, libm fixup unnecessary.
  g.x = __builtin_amdgcn_sqrtf(fmaf(gdx, gdx, fmaf(ghx, ghx, gwx * gwx)));
  g.y = __builtin_amdgcn_sqrtf(fmaf(gdy, gdy, fmaf(ghy, ghy, gwy * gwy)));
  g.z = __builtin_amdgcn_sqrtf(fmaf(gdz, gdz, fmaf(ghz, ghz, gwz * gwz)));
  g.w = __builtin_amdgcn_sqrtf(fmaf(gdw, gdw, fmaf(ghw, ghw, gww * gww)));
  return g;
}

__global__ __launch_bounds__(BLOCK) void sobel3d_mag_kernel(
    const float* __restrict__ x, float* __restrict__ out) {
  const int col2 = blockIdx.x * BLOCK + threadIdx.x;  // (row-pair, q), 0..3199
  const int hh = col2 / W4q;   // 0..79
  const int q = col2 - hh * W4q;
  const int h0 = hh * 2;       // first output row
  const int w4 = q * 4;
  const int bc = blockIdx.z;
  const int d0 = blockIdx.y * DCHUNK;

  const float* xb = x + (size_t)bc * Dn * HWn;
  float* ob = out + (size_t)bc * Dn * HWn;

  // Input rows h0-1 .. h0+2 with replicate clamp.
  const int rA = (h0 > 0 ? h0 - 1 : 0) * Wn;
  const int rB = h0 * Wn;
  const int rC = (h0 + 1) * Wn;
  const int rD = (h0 + 2 < Hn ? h0 + 2 : Hn - 1) * Wn;

  const int lane = threadIdx.x & 63;
  const bool ql = (q == 0);
  const bool qr = (q == W4q - 1);
  const bool fixL = (lane == 0) && !ql;
  const bool fixR = (lane == 63) && !qr;

  Plane2 P0 = load_plane2(xb, d0 - 1, rA, rB, rC, rD, w4, ql, qr, fixL, fixR);
  Plane2 P1 = load_plane2(xb, d0, rA, rB, rC, rD, w4, ql, qr, fixL, fixR);

#pragma unroll
  for (int i = 0; i < DCHUNK; ++i) {
    const int z = d0 + i;
    Plane2 P2 = load_plane2(xb, z + 1, rA, rB, rC, rD, w4, ql, qr, fixL, fixR);
    float* o0 = ob + (size_t)z * HWn + rB + w4;
    float* o1 = ob + (size_t)z * HWn + rC + w4;
    // Output never re-read: nontemporal keeps input resident in L2/LLC.
    __builtin_nontemporal_store(mag4(P0.a, P1.a, P2.a), (f32x4*)o0);
    __builtin_nontemporal_store(mag4(P0.b, P1.b, P2.b), (f32x4*)o1);
    P0 = P1;
    P1 = P2;
  }
}

extern "C" void kernel_launch(void* const* d_in, const int* in_sizes, int n_in,
                              void* d_out, int out_size, void* d_ws, size_t ws_size,
                              hipStream_t stream) {
  const float* x = (const float*)d_in[0];
  float* out = (float*)d_out;

  dim3 block(BLOCK);
  dim3 grid(COLS2 / BLOCK, Dn / DCHUNK, BCn);  // (25, 32, 4) = 3200 blocks
  sobel3d_mag_kernel<<<grid, block, 0, stream>>>(x, out);
}

// Round 9
// 29.310 us; speedup vs baseline: 1.2429x; 1.2429x over previous
//
#include <hip/hip_runtime.h>
#include <math.h>

// Problem constants (from reference: x = (2,2,160,160,160) fp32)
#define BCn 4
#define Dn 160
#define Hn 160
#define Wn 160
#define HWn (Hn * Wn)
#define W4q (Wn / 4)        // 40 float4 groups per row
#define COLS (Hn * W4q)     // 6400 (h, q) columns per plane
#define DCHUNK 5
#define NZC (Dn / DCHUNK)   // 32 z-chunks
#define XBLK (COLS / 256)   // 25 x-blocks per work-row
#define NWR (NZC * BCn)     // 128 work-rows (z-chunk, channel)
#define BLOCK 256

// Native clang vector for __builtin_nontemporal_store (HIP float4 rejected).
typedef float f32x4 __attribute__((ext_vector_type(4)));

// Reduced per-plane state for 4 consecutive W outputs:
//   Rs = 3x3 window sums (feeds gd), Rd = row(h+1)-row(h-1) sums (feeds gh),
//   Cs = col(w+1)-col(w-1) sums (feeds gw).
struct Plane {
  float4 Rs, Rd, Cs;
};

// One z-plane: 3 coalesced float4 loads; w-halo via neighbor-lane shuffles
// (the R6 win: avoids 6 scalar loads' L1 line-touches).
__device__ __forceinline__ Plane load_plane(const float* __restrict__ xb, int zz,
                                            int rm, int r0, int rp, int w4,
                                            bool ql, bool qr, bool fixL, bool fixR) {
  const int zc = zz < 0 ? 0 : (zz > Dn - 1 ? Dn - 1 : zz);
  const float* p = xb + (size_t)zc * HWn;

  const float4 vm = *(const float4*)(p + rm + w4);
  const float4 v0 = *(const float4*)(p + r0 + w4);
  const float4 vp = *(const float4*)(p + rp + w4);

  float lA = __shfl_up(vm.w, 1);
  float lB = __shfl_up(v0.w, 1);
  float lC = __shfl_up(vp.w, 1);
  float rA = __shfl_down(vm.x, 1);
  float rB = __shfl_down(v0.x, 1);
  float rC = __shfl_down(vp.x, 1);

  if (fixL) {
    lA = p[rm + w4 - 1];
    lB = p[r0 + w4 - 1];
    lC = p[rp + w4 - 1];
  }
  if (fixR) {
    rA = p[rm + w4 + 4];
    rB = p[r0 + w4 + 4];
    rC = p[rp + w4 + 4];
  }

  const float m0 = ql ? vm.x : lA;
  const float c0 = ql ? v0.x : lB;
  const float q0 = ql ? vp.x : lC;
  const float m5 = qr ? vm.w : rA;
  const float c5 = qr ? v0.w : rB;
  const float q5 = qr ? vp.w : rC;

  const float s0 = m0 + c0 + q0;
  const float s1 = vm.x + v0.x + vp.x;
  const float s2 = vm.y + v0.y + vp.y;
  const float s3 = vm.z + v0.z + vp.z;
  const float s4 = vm.w + v0.w + vp.w;
  const float s5 = m5 + c5 + q5;
  const float d0 = q0 - m0;
  const float d1 = vp.x - vm.x;
  const float d2 = vp.y - vm.y;
  const float d3 = vp.z - vm.z;
  const float d4 = vp.w - vm.w;
  const float d5 = q5 - m5;

  Plane out;
  const float t12 = s1 + s2, t23 = s2 + s3, t34 = s3 + s4;
  out.Rs.x = s0 + t12;
  out.Rs.y = t12 + s3;
  out.Rs.z = t23 + s4;
  out.Rs.w = t34 + s5;
  const float u12 = d1 + d2, u23 = d2 + d3, u34 = d3 + d4;
  out.Rd.x = d0 + u12;
  out.Rd.y = u12 + d3;
  out.Rd.z = u23 + d4;
  out.Rd.w = u34 + d5;
  out.Cs.x = s2 - s0;
  out.Cs.y = s3 - s1;
  out.Cs.z = s4 - s2;
  out.Cs.w = s5 - s3;
  return out;
}

__device__ __forceinline__ f32x4 mag4(const Plane& P0, const Plane& P1,
                                      const Plane& P2) {
  const float gdx = P2.Rs.x - P0.Rs.x;
  const float gdy = P2.Rs.y - P0.Rs.y;
  const float gdz = P2.Rs.z - P0.Rs.z;
  const float gdw = P2.Rs.w - P0.Rs.w;
  const float ghx = P0.Rd.x + P1.Rd.x + P2.Rd.x;
  const float ghy = P0.Rd.y + P1.Rd.y + P2.Rd.y;
  const float ghz = P0.Rd.z + P1.Rd.z + P2.Rd.z;
  const float ghw = P0.Rd.w + P1.Rd.w + P2.Rd.w;
  const float gwx = P0.Cs.x + P1.Cs.x + P2.Cs.x;
  const float gwy = P0.Cs.y + P1.Cs.y + P2.Cs.y;
  const float gwz = P0.Cs.z + P1.Cs.z + P2.Cs.z;
  const float gww = P0.Cs.w + P1.Cs.w + P2.Cs.w;
  f32x4 g;
  // Raw v_sqrt_f32 — abs threshold 0.555, libm fixup unnecessary.
  g.x = __builtin_amdgcn_sqrtf(fmaf(gdx, gdx, fmaf(ghx, ghx, gwx * gwx)));
  g.y = __builtin_amdgcn_sqrtf(fmaf(gdy, gdy, fmaf(ghy, ghy, gwy * gwy)));
  g.z = __builtin_amdgcn_sqrtf(fmaf(gdz, gdz, fmaf(ghz, ghz, gwz * gwz)));
  g.w = __builtin_amdgcn_sqrtf(fmaf(gdw, gdw, fmaf(ghw, ghw, gww * gww)));
  return g;
}

__global__ __launch_bounds__(BLOCK) void sobel3d_mag_kernel(
    const float* __restrict__ x, float* __restrict__ out) {
  // XCD-locality swizzle (bijective: 3200 % 8 == 0). HW round-robins flat
  // block id F over 8 XCDs (F % 8 = xcd). We remap so all 25 x-blocks of a
  // work-row (z-chunk, channel) share one XCD: their 7 planes (~716 KB) and
  // 3x h-shared rows then hit that XCD's L2 (~200 cy) instead of LLC/HBM
  // (450-900 cy) — attacking the measured ~2600 cy/iter latency wall.
  const int F = blockIdx.x;          // 0..3199
  const int k = F & 7;               // xcd (heuristic)
  const int j = F >> 3;              // 0..399
  const int bx = j % XBLK;           // x-block within work-row
  const int wr = (j / XBLK) * 8 + k; // work-row 0..127, stays on xcd k
  const int zc_idx = wr & (NZC - 1); // 32 z-chunks
  const int bc = wr >> 5;            // channel 0..3

  const int col4 = bx * BLOCK + threadIdx.x;  // (h, q), 0..6399
  const int h = col4 / W4q;
  const int q = col4 - h * W4q;
  const int w4 = q * 4;
  const int d0 = zc_idx * DCHUNK;

  const float* xb = x + (size_t)bc * Dn * HWn;
  float* ob = out + (size_t)bc * Dn * HWn;

  const int hm = (h > 0) ? h - 1 : 0;
  const int hp = (h < Hn - 1) ? h + 1 : Hn - 1;
  const int rm = hm * Wn;
  const int r0 = h * Wn;
  const int rp = hp * Wn;

  const int lane = threadIdx.x & 63;
  const bool ql = (q == 0);
  const bool qr = (q == W4q - 1);
  const bool fixL = (lane == 0) && !ql;
  const bool fixR = (lane == 63) && !qr;

  Plane P0 = load_plane(xb, d0 - 1, rm, r0, rp, w4, ql, qr, fixL, fixR);
  Plane P1 = load_plane(xb, d0, rm, r0, rp, w4, ql, qr, fixL, fixR);

#pragma unroll
  for (int i = 0; i < DCHUNK; ++i) {
    const int z = d0 + i;
    Plane P2 = load_plane(xb, z + 1, rm, r0, rp, w4, ql, qr, fixL, fixR);
    // Output never re-read: nontemporal keeps input resident in L2/LLC.
    __builtin_nontemporal_store(mag4(P0, P1, P2),
                                (f32x4*)(ob + (size_t)z * HWn + r0 + w4));
    P0 = P1;
    P1 = P2;
  }
}

extern "C" void kernel_launch(void* const* d_in, const int* in_sizes, int n_in,
                              void* d_out, int out_size, void* d_ws, size_t ws_size,
                              hipStream_t stream) {
  const float* x = (const float*)d_in[0];
  float* out = (float*)d_out;

  dim3 block(BLOCK);
  dim3 grid(XBLK * NZC * BCn);  // flat 3200 blocks; swizzle decoded in-kernel
  sobel3d_mag_kernel<<<grid, block, 0, stream>>>(x, out);
}